// Round 9
// baseline (136.272 us; speedup 1.0000x reference)
//
#include <hip/hip_runtime.h>

// Problem constants (fixed by setup_inputs): B=64, T=1024, V=128, S=256
constexpr int B_ = 64;
constexpr int T_ = 1024;
constexpr int V_ = 128;
constexpr int S_ = 256;
constexpr int GRING = 64;            // staged rows (16 blocks of 4)
constexpr int NTAG = 16;             // tag slots (1 per in-flight block)
constexpr int RW = 128;              // floats per staged row: full exp'd vocab row
constexpr int NGW = 2;               // producer waves (trivially light now)
constexpr float INV_LN2 = 1.4426950408889634f;
constexpr float LN2 = 0.6931471805599453f;

// Workspace layout (floats): [0..63] per-b loss; [64 ..) dumps: fwd b*640,
// then bwd at +64*640; K exponents as ints after that (fwd [b], bwd [64+b]).
#define WS_DUMPF(W, b) ((W) + 64 + (size_t)(b) * 640)
#define WS_DUMPB(W, b) ((W) + 64 + 64 * 640 + (size_t)(b) * 640)
#define WS_KARR(W)     ((int*)((W) + 64 + 2 * 64 * 640))

#define WG_SCOPE __HIP_MEMORY_SCOPE_WORKGROUP

__device__ __forceinline__ void poll_eq(int* p, int want) {
    // RELAXED: LDS is physically shared per-CU; producer drained its ds_writes
    // (explicit lgkmcnt(0)) before the tag became visible.
    while (__hip_atomic_load(p, __ATOMIC_RELAXED, WG_SCOPE) != want)
        __builtin_amdgcn_s_sleep(1);
}

// ---- DPP cross-lane helpers (pure VALU: no DS op, no lgkmcnt) ----
template <int CTRL>
__device__ __forceinline__ float dpp_mov0(float x) {
    // invalid source lanes receive old = 0 (wave_shr1: lane0 -> 0;
    // wave_shl1: lane63 -> 0) -- exactly the boundary fill the scan needs.
    return __int_as_float(__builtin_amdgcn_update_dpp(
        0, __float_as_int(x), CTRL, 0xF, 0xF, false));
}
template <int CTRL>
__device__ __forceinline__ float dpp_max(float x) {
    const float s = __int_as_float(__builtin_amdgcn_update_dpp(
        __float_as_int(x), __float_as_int(x), CTRL, 0xF, 0xF, false));
    return fmaxf(x, s);
}

// Wave-uniform rescale: pin wave max to 2^124 (R8-proven; cadence <= 8 rows).
// R13: wave-max via DPP reduce (row_shr 1/2/4/8 + bcast15/31 -> lane63).
__device__ __forceinline__ int wave_rescale(float a[10], int& K) {
    float mx = a[0];
    #pragma unroll
    for (int k = 1; k < 10; ++k) mx = fmaxf(mx, a[k]);
    mx = dpp_max<0x111>(mx);   // row_shr:1
    mx = dpp_max<0x112>(mx);   // row_shr:2
    mx = dpp_max<0x114>(mx);   // row_shr:4
    mx = dpp_max<0x118>(mx);   // row_shr:8
    mx = dpp_max<0x142>(mx);   // row_bcast:15
    mx = dpp_max<0x143>(mx);   // row_bcast:31 -> lane63 has wave-max
    const float mall = __int_as_float(
        __builtin_amdgcn_readlane(__float_as_int(mx), 63));
    int e;
    (void)frexpf(mall, &e);
    const int ks = (mall > 0.0f) ? (124 - e) : 0;
    #pragma unroll
    for (int k = 0; k < 10; ++k) a[k] = ldexpf(a[k], ks);
    K += ks;
    return ks;
}

// R18: ZERO-BPERMUTE LAYOUT. R13/R16/R17 triangulated the floor to the
// consumer-side serial loop with an unexplained ~200cy/row beyond issue
// counts -- the least-modeled ops are the 10 wave-wide ds_bpermutes/row
// (producers) + 12 ds_read_b64/block (consumer) in one in-order DS queue.
// New layout: producers just exp the full 128-float row into LDS
// (2 exp + 1 ds_write_b64/row -- 6x lighter); the consumer gathers its 6
// values/row by DIVERGENT ds_read_b32 at per-lane constant label offsets
// (labels fixed over time). System DS ops/row: 16 -> 8; bpermutes: 10 -> 0.
// Protocol = R17 elastic tags (proven). 128 WGs x 3 waves, 1 dir/WG.
__global__ __launch_bounds__(192) void ctc_scan(
    const float* __restrict__ lp,      // [B,T,V] natural-log softmax
    const int* __restrict__ in_len,    // [B]
    const int* __restrict__ tgt,       // [B,S]
    const int* __restrict__ tgt_len,   // [B]
    float* __restrict__ W)             // workspace
{
    const int b    = blockIdx.x & 63;
    const int dir  = blockIdx.x >> 6;         // 0 = fwd, 1 = bwd
    const int tid  = threadIdx.x;
    const int wid  = tid >> 6;
    const int lane = tid & 63;

    __shared__ float ring[GRING * RW];        // 32 KB
    __shared__ int   tags[NTAG];
    __shared__ int   cons;

    const int L  = tgt_len[b];        // 64..256
    const int Tb = in_len[b];         // 768..1024
    const float* lpb = lp + (size_t)b * T_ * V_;
    const int* tg = tgt + b * S_;

    const int tm = (Tb - 2) >> 1;
    const int Uf = tm;                // fwd steps: u=1..Uf (row t=u) -> alpha_tm
    const int Ub = Tb - 2 - tm;       // bwd steps: u=1..Ub (row t=Tb-1-u) -> g_{tm+1}
    const int U  = dir ? Ub : Uf;

    if (tid == 0) cons = 0;
    if (tid < NTAG) tags[tid] = -1;
    __syncthreads();

    if (wid >= 1) {
        // ======================= producers =======================
        // wave q handles blocks m == q (mod 2); per row: coalesced float2
        // load -> 2 exps -> 1 ds_write_b64. No gather, no bpermute.
        const int q = wid - 1;                    // 0..1

        float2 R0[4], R1[4];
        auto issue = [&](float2 (&Rb)[4], int m) {
            const int n = min(4, U - 4 * m);
            #pragma unroll
            for (int r = 0; r < 4; ++r) {
                if (r < n) {
                    const int u = 4 * m + 1 + r;
                    const int t = dir ? (Tb - 1 - u) : u;
                    Rb[r] = *(const float2*)(lpb + (size_t)t * V_ + 2 * lane);
                }
            }
        };
        // block m covers rows u = 4m+1 .. 4m+4; row u lives at slot (u-1)&63
        auto process = [&](float2 (&Rb)[4], int m) {
            // ring-slot reuse gate: slot shared with block m-16
            while (__hip_atomic_load(&cons, __ATOMIC_RELAXED, WG_SCOPE) < 4 * m - 60)
                __builtin_amdgcn_s_sleep(1);
            const int n = min(4, U - 4 * m);
            #pragma unroll
            for (int r = 0; r < 4; ++r) {
                if (r < n) {
                    const float e0 = __builtin_exp2f(Rb[r].x * INV_LN2);
                    const float e1 = __builtin_exp2f(Rb[r].y * INV_LN2);
                    float* rb = ring + ((4 * m + r) & (GRING - 1)) * RW;
                    ((float2*)rb)[lane] = make_float2(e0, e1);
                }
            }
            // drain LDS writes only (NOT vmcnt -- prefetched global loads stay
            // in flight), then publish the tag.
            asm volatile("s_waitcnt lgkmcnt(0)" ::: "memory");
            if (lane == 0)
                __hip_atomic_store(&tags[m & (NTAG - 1)], m, __ATOMIC_RELAXED, WG_SCOPE);
        };

        int m = q;
        if (4 * m + 1 <= U) {
            issue(R0, m);
            if (4 * (m + NGW) + 1 <= U) issue(R1, m + NGW);
            while (true) {
                process(R0, m);
                if (4 * (m + 2 * NGW) + 1 <= U) issue(R0, m + 2 * NGW);
                m += NGW;
                if (4 * m + 1 > U) break;
                process(R1, m);
                if (4 * (m + 2 * NGW) + 1 <= U) issue(R1, m + 2 * NGW);
                m += NGW;
                if (4 * m + 1 > U) break;
            }
        }
        return;
    }

    // ======================= consumer (wave0) =======================
    // Per-lane constant gather offsets: word off[c] = tg[5*lane+c] (0 if j>=L,
    // masked by vmask at use). Blank = word 0 of the row (uniform broadcast).
    int   off[5];
    float vmask[5];
    #pragma unroll
    for (int c = 0; c < 5; ++c) {
        const int j = 5 * lane + c;
        if (j < L) { off[c] = tg[j]; vmask[c] = 1.0f; }
        else       { off[c] = 0;     vmask[c] = 0.0f; }
    }

    float S2[2][24];   // [set][r*6 + v], v: 0=blank, 1..5 = label gathers
    auto readBlock = [&](int set, int m) {
        const int base = ((4 * m) & (GRING - 1)) * RW;
        #pragma unroll
        for (int r = 0; r < 4; ++r) {
            S2[set][r * 6 + 0] = ring[base + r * RW];          // uniform -> bcast
            #pragma unroll
            for (int c = 0; c < 5; ++c)
                S2[set][r * 6 + 1 + c] = ring[base + r * RW + off[c]];
        }
    };
    auto readRowDirect = [&](int u, float (&v)[6]) {
        const int base = ((u - 1) & (GRING - 1)) * RW;
        v[0] = ring[base];
        #pragma unroll
        for (int c = 0; c < 5; ++c) v[1 + c] = ring[base + off[c]];
    };

    if (dir == 0) {
        // -------- forward alpha --------
        float skipf[5];
        #pragma unroll
        for (int c = 0; c < 5; ++c) {
            const int j = 5 * lane + c;
            skipf[c] = (j >= 1 && j < L && tg[j] != tg[j - 1]) ? 1.0f : 0.0f;
        }
        float a[10];
        #pragma unroll
        for (int k = 0; k < 10; ++k) a[k] = 0.0f;
        {
            const float p00 = __builtin_exp2f(lpb[0] * INV_LN2);
            const float p01 = __builtin_exp2f(lpb[tg[0]] * INV_LN2);
            if (lane == 0) { a[0] = p00; a[1] = p01; }
        }
        float u9n = 0.0f;             // inflow alpha_prev[s-1] for s=10*lane
        int K = 0;

        auto rowCore = [&](float2 c0, float2 c1, float2 c2) {
            const float u9 = u9n;
            const float p0 = c0.x;
            a[9] = (a[9] + a[8] + skipf[4] * a[7]) * c2.y;
            u9n = dpp_mov0<0x138>(a[9]);   // wave_shr:1 (lane0 -> 0)
            a[8] = (a[8] + a[7]) * p0;
            a[7] = (a[7] + a[6] + skipf[3] * a[5]) * c2.x;
            a[6] = (a[6] + a[5]) * p0;
            a[5] = (a[5] + a[4] + skipf[2] * a[3]) * c1.y;
            a[4] = (a[4] + a[3]) * p0;
            a[3] = (a[3] + a[2] + skipf[1] * a[1]) * c1.x;
            a[2] = (a[2] + a[1]) * p0;
            a[1] = (a[1] + a[0] + skipf[0] * u9) * c0.y;
            a[0] = (a[0] + u9) * p0;
        };
        auto row4 = [&](int set) {
            #pragma unroll
            for (int r = 0; r < 4; ++r)
                rowCore(make_float2(S2[set][r*6+0], vmask[0]*S2[set][r*6+1]),
                        make_float2(vmask[1]*S2[set][r*6+2], vmask[2]*S2[set][r*6+3]),
                        make_float2(vmask[3]*S2[set][r*6+4], vmask[4]*S2[set][r*6+5]));
        };
        auto body = [&](int m, int setc, int setp) {
            if (4 * (m + 1) + 1 <= Uf) {
                poll_eq(&tags[(m + 1) & (NTAG - 1)], m + 1);
                readBlock(setp, m + 1);
            }
            row4(setc);
            if (lane == 0)
                __hip_atomic_store(&cons, 4 * m + 4, __ATOMIC_RELAXED, WG_SCOPE);
        };

        const int MB2 = (Uf / 4) & ~1;
        poll_eq(&tags[0], 0); readBlock(0, 0);
        for (int mb = 0; mb < MB2; mb += 2) {
            body(mb + 0, 0, 1);
            body(mb + 1, 1, 0);
            { const int ks = wave_rescale(a, K); u9n = ldexpf(u9n, ks); }  // 8 rows
        }
        // tail: staged block MB2 (set0, if present), then direct ring rows
        #pragma unroll
        for (int r = 0; r < 4; ++r)
            if (4 * MB2 + 1 + r <= Uf)
                rowCore(make_float2(S2[0][r*6+0], vmask[0]*S2[0][r*6+1]),
                        make_float2(vmask[1]*S2[0][r*6+2], vmask[2]*S2[0][r*6+3]),
                        make_float2(vmask[3]*S2[0][r*6+4], vmask[4]*S2[0][r*6+5]));
        for (int u = 4 * (MB2 + 1) + 1; u <= Uf; ++u) {                    // <=3 rows
            const int bu = (u - 1) >> 2;
            poll_eq(&tags[bu & (NTAG - 1)], bu);
            float v[6];
            readRowDirect(u, v);
            rowCore(make_float2(v[0], vmask[0]*v[1]),
                    make_float2(vmask[1]*v[2], vmask[2]*v[3]),
                    make_float2(vmask[3]*v[4], vmask[4]*v[5]));
        }
        { const int ks = wave_rescale(a, K); u9n = ldexpf(u9n, ks); }      // <=7 rows

        float* dump = WS_DUMPF(W, b);
        #pragma unroll
        for (int k = 0; k < 10; ++k) dump[10 * lane + k] = a[k];
        if (lane == 0) {
            WS_KARR(W)[b] = K;
            __hip_atomic_store(&cons, Uf + 64, __ATOMIC_RELAXED, WG_SCOPE);
        }
    } else {
        // -------- backward beta --------
        float sB[5];                  // skip into s+2 (odd): label j = 5*lane+c+1
        #pragma unroll
        for (int c = 0; c < 5; ++c) {
            const int j = 5 * lane + c + 1;
            sB[c] = (j < L && tg[j] != tg[j - 1]) ? 1.0f : 0.0f;
        }
        float g[10];
        #pragma unroll
        for (int k = 0; k < 10; ++k) g[k] = 0.0f;
        {   // g_{Tb-1}: nonzero at s=2L (blank) and s=2L-1 (last label)
            const float pb = __builtin_exp2f(lpb[(size_t)(Tb - 1) * V_] * INV_LN2);
            const float pl = __builtin_exp2f(lpb[(size_t)(Tb - 1) * V_ + tg[L - 1]] * INV_LN2);
            #pragma unroll
            for (int k = 0; k < 10; ++k) {
                const int s = 10 * lane + k;
                if (s == 2 * L)     g[k] = pb;
                if (s == 2 * L - 1) g[k] = pl;
            }
        }
        float d0n = dpp_mov0<0x130>(g[0]);   // wave_shl:1 (lane63 -> 0)
        float d1n = dpp_mov0<0x130>(g[1]);
        int K = 0;

        auto rowCore = [&](float2 c0, float2 c1, float2 c2) {
            const float d0 = d0n, d1 = d1n;
            const float p0 = c0.x;
            g[0] = (g[0] + g[1]) * p0;
            g[1] = (g[1] + g[2] + sB[0] * g[3]) * c0.y;
            d0n = dpp_mov0<0x130>(g[0]);     // early-produce, pure VALU
            d1n = dpp_mov0<0x130>(g[1]);
            g[2] = (g[2] + g[3]) * p0;
            g[3] = (g[3] + g[4] + sB[1] * g[5]) * c1.x;
            g[4] = (g[4] + g[5]) * p0;
            g[5] = (g[5] + g[6] + sB[2] * g[7]) * c1.y;
            g[6] = (g[6] + g[7]) * p0;
            g[7] = (g[7] + g[8] + sB[3] * g[9]) * c2.x;
            g[8] = (g[8] + g[9]) * p0;
            g[9] = (g[9] + d0 + sB[4] * d1) * c2.y;
        };
        auto row4 = [&](int set) {
            #pragma unroll
            for (int r = 0; r < 4; ++r)
                rowCore(make_float2(S2[set][r*6+0], vmask[0]*S2[set][r*6+1]),
                        make_float2(vmask[1]*S2[set][r*6+2], vmask[2]*S2[set][r*6+3]),
                        make_float2(vmask[3]*S2[set][r*6+4], vmask[4]*S2[set][r*6+5]));
        };
        auto body = [&](int m, int setc, int setp) {
            if (4 * (m + 1) + 1 <= Ub) {
                poll_eq(&tags[(m + 1) & (NTAG - 1)], m + 1);
                readBlock(setp, m + 1);
            }
            row4(setc);
            if (lane == 0)
                __hip_atomic_store(&cons, 4 * m + 4, __ATOMIC_RELAXED, WG_SCOPE);
        };

        const int MB2 = (Ub / 4) & ~1;
        poll_eq(&tags[0], 0); readBlock(0, 0);
        for (int mb = 0; mb < MB2; mb += 2) {
            body(mb + 0, 0, 1);
            body(mb + 1, 1, 0);
            { const int ks = wave_rescale(g, K);
              d0n = ldexpf(d0n, ks); d1n = ldexpf(d1n, ks); }
        }
        #pragma unroll
        for (int r = 0; r < 4; ++r)
            if (4 * MB2 + 1 + r <= Ub)
                rowCore(make_float2(S2[0][r*6+0], vmask[0]*S2[0][r*6+1]),
                        make_float2(vmask[1]*S2[0][r*6+2], vmask[2]*S2[0][r*6+3]),
                        make_float2(vmask[3]*S2[0][r*6+4], vmask[4]*S2[0][r*6+5]));
        for (int u = 4 * (MB2 + 1) + 1; u <= Ub; ++u) {
            const int bu = (u - 1) >> 2;
            poll_eq(&tags[bu & (NTAG - 1)], bu);
            float v[6];
            readRowDirect(u, v);
            rowCore(make_float2(v[0], vmask[0]*v[1]),
                    make_float2(vmask[1]*v[2], vmask[2]*v[3]),
                    make_float2(vmask[3]*v[4], vmask[4]*v[5]));
        }
        { const int ks = wave_rescale(g, K);
          d0n = ldexpf(d0n, ks); d1n = ldexpf(d1n, ks); }

        {   // combine: gext[s] = g[s] + g[s+1] + skip[s+2]*g[s+2] (ascending)
            const float d0 = d0n, d1 = d1n;
            g[0] = g[0] + g[1];
            g[1] = g[1] + g[2] + sB[0] * g[3];
            g[2] = g[2] + g[3];
            g[3] = g[3] + g[4] + sB[1] * g[5];
            g[4] = g[4] + g[5];
            g[5] = g[5] + g[6] + sB[2] * g[7];
            g[6] = g[6] + g[7];
            g[7] = g[7] + g[8] + sB[3] * g[9];
            g[8] = g[8] + g[9];
            g[9] = g[9] + d0 + sB[4] * d1;
        }
        float* dump = WS_DUMPB(W, b);
        #pragma unroll
        for (int k = 0; k < 10; ++k) dump[10 * lane + k] = g[k];
        if (lane == 0) {
            WS_KARR(W)[64 + b] = K;
            __hip_atomic_store(&cons, Ub + 64, __ATOMIC_RELAXED, WG_SCOPE);
        }
    }
}

// Join: one block per batch element, 64 lanes. Double-precision dot of the
// two dumps (factors span ~240 bits in f32 frames -- R7 lesson).
__global__ void ctc_join_kernel(const float* __restrict__ W_const,
                                const int* __restrict__ tgt_len,
                                float* __restrict__ lossArr) {
    const int b = blockIdx.x;
    const int lane = threadIdx.x;
    float* W = const_cast<float*>(W_const);
    const float* dA = WS_DUMPF(W, b);
    const float* dB = WS_DUMPB(W, b);
    double sum = 0.0;
    #pragma unroll
    for (int k = 0; k < 10; ++k)
        sum += (double)dA[10 * lane + k] * (double)dB[10 * lane + k];
    #pragma unroll
    for (int d = 1; d < 64; d <<= 1) sum += __shfl_xor(sum, d, 64);
    if (lane == 0) {
        const int L = tgt_len[b];
        const int KF = WS_KARR(W)[b];
        const int KB = WS_KARR(W)[64 + b];
        float loss = 0.0f;                     // infeasible (sum<=0) -> 0
        if (sum > 0.0) {
            const long long ub = __double_as_longlong(sum);
            const int ex = (int)((ub >> 52) & 2047) - 1023;
            const double f = __longlong_as_double(
                (ub & 0x000FFFFFFFFFFFFFLL) | 0x3FF0000000000000LL);
            const float ll2 = __builtin_log2f((float)f)
                            + (float)(ex - KF - KB);
            loss = -(ll2 * LN2);
            if (!(loss <= 1e29f)) loss = 0.0f; // zero_infinity
        }
        lossArr[b] = loss / (float)L;
    }
}

__global__ void ctc_reduce_kernel(const float* __restrict__ ws, float* __restrict__ out) {
    float v = ws[threadIdx.x];
    #pragma unroll
    for (int o = 32; o > 0; o >>= 1) v += __shfl_down(v, o);
    if (threadIdx.x == 0) out[0] = v / (float)B_;
}

extern "C" void kernel_launch(void* const* d_in, const int* in_sizes, int n_in,
                              void* d_out, int out_size, void* d_ws, size_t ws_size,
                              hipStream_t stream) {
    const float* lp      = (const float*)d_in[0];
    const int*   in_len  = (const int*)d_in[1];
    const int*   tgt     = (const int*)d_in[2];
    const int*   tgt_len = (const int*)d_in[3];
    float* W   = (float*)d_ws;                  // needs ~330 KB
    float* out = (float*)d_out;

    ctc_scan<<<2 * B_, 192, 0, stream>>>(lp, in_len, tgt, tgt_len, W);
    ctc_join_kernel<<<B_, 64, 0, stream>>>(W, tgt_len, W);   // writes W[0..63]
    ctc_reduce_kernel<<<1, 64, 0, stream>>>(W, out);
}